// Round 1
// 270.013 us; speedup vs baseline: 1.1404x; 1.1404x over previous
//
#include <hip/hip_runtime.h>

#define N_NODES 40000
#define N_EDGES 640000
#define DIM 128
#define N_LAYERS 3

typedef _Float16 half_t;
typedef __attribute__((ext_vector_type(8))) _Float16 f16x8_t;
typedef __attribute__((ext_vector_type(4))) float f32x4_t;

// ---------------- preprocessing: CSR by dst ----------------

__global__ void hist_kernel(const int* __restrict__ dst, int* __restrict__ deg) {
    int i = blockIdx.x * blockDim.x + threadIdx.x;
    if (i < N_EDGES) atomicAdd(&deg[dst[i]], 1);
}

__global__ void scan1_kernel(const int* __restrict__ deg, int* __restrict__ offsets,
                             float* __restrict__ inv_deg, int* __restrict__ bsum) {
    __shared__ int sd[256];
    int t = threadIdx.x, i = blockIdx.x * 256 + t;
    int v = (i < N_NODES) ? deg[i] : 0;
    if (i < N_NODES) inv_deg[i] = 1.0f / fmaxf((float)v, 1.0f);
    sd[t] = v;
    __syncthreads();
#pragma unroll
    for (int off = 1; off < 256; off <<= 1) {
        int x = (t >= off) ? sd[t - off] : 0;
        __syncthreads();
        sd[t] += x;
        __syncthreads();
    }
    if (i < N_NODES) offsets[i] = sd[t] - v;  // block-local exclusive
    if (t == 255) bsum[blockIdx.x] = sd[255];
}

__global__ void scan2_kernel(const int* __restrict__ bsum, int* __restrict__ boff) {
    __shared__ int sd[256];
    const int nb = (N_NODES + 255) / 256;
    int t = threadIdx.x;
    int v = (t < nb) ? bsum[t] : 0;
    sd[t] = v;
    __syncthreads();
#pragma unroll
    for (int off = 1; off < 256; off <<= 1) {
        int x = (t >= off) ? sd[t - off] : 0;
        __syncthreads();
        sd[t] += x;
        __syncthreads();
    }
    if (t < nb) boff[t] = sd[t] - v;
}

__global__ void scan3_kernel(int* __restrict__ offsets, const int* __restrict__ deg,
                             const int* __restrict__ boff) {
    int i = blockIdx.x * 256 + threadIdx.x;
    if (i < N_NODES) {
        int o = offsets[i] + boff[blockIdx.x];
        offsets[i] = o;
        if (i == N_NODES - 1) offsets[N_NODES] = o + deg[i];
    }
}

__global__ void scatter_kernel(const int* __restrict__ src, const int* __restrict__ dst,
                               const int* __restrict__ offsets, int* __restrict__ cursor,
                               int* __restrict__ csr_src) {
    int i = blockIdx.x * blockDim.x + threadIdx.x;
    if (i < N_EDGES) {
        int d = dst[i];
        int pos = atomicAdd(&cursor[d], 1);
        csr_src[offsets[d] + pos] = src[i];
    }
}

// ---------------- fused prep: x -> fp16, W[k][n] f32 -> Wt[l][s][n][k] f16 ----------------
__global__ void prep_kernel(const float* __restrict__ x, half_t* __restrict__ h,
                            const float* __restrict__ w_self, const float* __restrict__ w_neigh,
                            half_t* __restrict__ wt) {
    int i = blockIdx.x * 256 + threadIdx.x;
    const int NS = N_NODES * DIM / 8;  // 640000 8-float chunks
    if (i < NS) {
        const float4* p = (const float4*)x + (size_t)i * 2;
        float4 a = p[0], b = p[1];
        f16x8_t v;
        v[0] = (half_t)a.x; v[1] = (half_t)a.y; v[2] = (half_t)a.z; v[3] = (half_t)a.w;
        v[4] = (half_t)b.x; v[5] = (half_t)b.y; v[6] = (half_t)b.z; v[7] = (half_t)b.w;
        *(f16x8_t*)&h[(size_t)i * 8] = v;
    } else {
        int j = i - NS;
        if (j < N_LAYERS * 2 * DIM * DIM) {
            int k = j & (DIM - 1);
            int n = (j >> 7) & (DIM - 1);
            int ls = j >> 14;
            int l = ls >> 1, s = ls & 1;
            const float* W = (s ? w_neigh : w_self) + (size_t)l * DIM * DIM;
            wt[j] = (half_t)W[k * DIM + n];  // transposed: Wt[n][k]
        }
    }
}

// ---------------- mean aggregation: fp16 gather (256B rows), fp32 accumulate ----------------
// one wave per node; 16 lanes per row (16B f16x8 each), 4 edge-groups, 16 edges
// (4 independent row-loads) in flight per loop iteration -> 1 latency round for deg<=16.
__global__ void agg_kernel(const half_t* __restrict__ h,
                           const int* __restrict__ offsets,
                           const int* __restrict__ csr_src, const float* __restrict__ inv_deg,
                           half_t* __restrict__ agg) {
    int node = (blockIdx.x * blockDim.x + threadIdx.x) >> 6;
    int lane = threadIdx.x & 63;
    if (node >= N_NODES) return;
    const int g = lane >> 4, c = lane & 15;  // edge-group, 16B column chunk
    int e0 = offsets[node], e1 = offsets[node + 1];
    float acc[8] = {0.f, 0.f, 0.f, 0.f, 0.f, 0.f, 0.f, 0.f};
    for (int base = e0; base < e1; base += 16) {
        float f[4];
        f16x8_t v[4];
#pragma unroll
        for (int s = 0; s < 4; ++s) {
            int ee = base + 4 * s + g;
            bool ok = ee < e1;
            f[s] = ok ? 1.f : 0.f;
            int sidx = ok ? csr_src[ee] : 0;
            v[s] = *(const f16x8_t*)&h[(size_t)sidx * DIM + c * 8];
        }
#pragma unroll
        for (int s = 0; s < 4; ++s)
#pragma unroll
            for (int j = 0; j < 8; ++j)
                acc[j] = fmaf(f[s], (float)v[s][j], acc[j]);
    }
#pragma unroll
    for (int j = 0; j < 8; ++j) {
        acc[j] += __shfl_xor(acc[j], 16, 64);
        acc[j] += __shfl_xor(acc[j], 32, 64);
    }
    if (g == 0) {
        float w = inv_deg[node];
        f16x8_t o;
#pragma unroll
        for (int j = 0; j < 8; ++j) o[j] = (half_t)(acc[j] * w);
        *(f16x8_t*)&agg[(size_t)node * DIM + c * 8] = o;
    }
}

// ---------------- fused dual GEMM, single-pass fp16 MFMA ----------------
// out = h @ Wself + agg @ Wneigh + b. Both W matrices staged once (full K) in LDS:
// 2*128*136*2B = 69.6 KB -> 2 blocks/CU, ONE barrier. Block: 256 thr = 4 waves,
// 128 rows x 128 cols; wave: 32 rows (2 rt) x 8 jt-tiles.
#define LDSN 136  // 128 + 8 pad halves: B-frag reads land 2-way max bank alias (free)
__global__ __launch_bounds__(256) void gemm_kernel(
    const half_t* __restrict__ h, const half_t* __restrict__ agg,
    const half_t* __restrict__ wt,  // this layer: [2][128][128] (n-major, k contiguous)
    const float* __restrict__ bias, float* __restrict__ fout,
    half_t* __restrict__ hout, int write_f32, int relu) {
    __shared__ half_t sW[2 * DIM][LDSN];
    const int tid = threadIdx.x;
    const int wave = tid >> 6, lane = tid & 63;
    const int quad = lane >> 4, m = lane & 15;
    const int rowW = blockIdx.x * 128 + wave * 32;

    // stage both W matrices, full K (4096 16B chunks / 256 threads = 16 each)
#pragma unroll
    for (int c4 = 0; c4 < 16; ++c4) {
        int c = (c4 << 8) + tid;
        int part = c & 15;   // 16B chunk within 256B row
        int n = c >> 4;      // 0..255 = s*128+n
        *(f16x8_t*)&sW[n][part * 8] = *(const f16x8_t*)&wt[(size_t)n * DIM + part * 8];
    }
    __syncthreads();

    f32x4_t acc[2][8];
#pragma unroll
    for (int a = 0; a < 2; ++a)
#pragma unroll
        for (int b = 0; b < 8; ++b) acc[a][b] = {0.f, 0.f, 0.f, 0.f};

    for (int s = 0; s < 2; ++s) {
        const half_t* A = s ? agg : h;
        const int nb = s * DIM;
#pragma unroll
        for (int k2 = 0; k2 < 4; ++k2) {
            const int kg = (k2 << 5) + quad * 8;
            f16x8_t B[8];
#pragma unroll
            for (int jt = 0; jt < 8; ++jt)
                B[jt] = *(const f16x8_t*)&sW[nb + jt * 16 + m][kg];
#pragma unroll
            for (int rt = 0; rt < 2; ++rt) {
                int r = rowW + rt * 16 + m;
                r = (r < N_NODES) ? r : (N_NODES - 1);  // clamp; stores guarded later
                f16x8_t a = *(const f16x8_t*)&A[(size_t)r * DIM + kg];
#pragma unroll
                for (int jt = 0; jt < 8; ++jt)
                    acc[rt][jt] = __builtin_amdgcn_mfma_f32_16x16x32_f16(a, B[jt], acc[rt][jt], 0, 0, 0);
            }
        }
    }

    // epilogue: C/D layout col=lane&15, row=quad*4+reg  [m89-verified]
#pragma unroll
    for (int rt = 0; rt < 2; ++rt)
#pragma unroll
        for (int jt = 0; jt < 8; ++jt) {
            int col = jt * 16 + m;
            float bv = bias[col];
#pragma unroll
            for (int r4 = 0; r4 < 4; ++r4) {
                int row = rowW + rt * 16 + quad * 4 + r4;
                if (row >= N_NODES) continue;
                float v = acc[rt][jt][r4] + bv;
                if (relu) v = fmaxf(v, 0.f);
                if (write_f32) {
                    fout[(size_t)row * DIM + col] = v;
                } else {
                    hout[(size_t)row * DIM + col] = (half_t)v;
                }
            }
        }
}

// ---------------- launch ----------------

extern "C" void kernel_launch(void* const* d_in, const int* in_sizes, int n_in,
                              void* d_out, int out_size, void* d_ws, size_t ws_size,
                              hipStream_t stream) {
    const float* x      = (const float*)d_in[0];
    const int*   src    = (const int*)d_in[1];
    const int*   dst    = (const int*)d_in[2];
    const float* w_self = (const float*)d_in[3];
    const float* w_neigh= (const float*)d_in[4];
    const float* b      = (const float*)d_in[5];
    float* out = (float*)d_out;

    // workspace carve (~24 MB)
    char* ws = (char*)d_ws;
    half_t* h    = (half_t*)ws; ws += (size_t)N_NODES * DIM * 2;
    half_t* agg  = (half_t*)ws; ws += (size_t)N_NODES * DIM * 2;
    half_t* wt   = (half_t*)ws; ws += (size_t)N_LAYERS * 2 * DIM * DIM * 2;
    int*   deg     = (int*)ws;  ws += (size_t)N_NODES * 4;
    int*   offsets = (int*)ws;  ws += (size_t)(N_NODES + 4) * 4;
    int*   cursor  = (int*)ws;  ws += (size_t)N_NODES * 4;
    int*   csr_src = (int*)ws;  ws += (size_t)N_EDGES * 4;
    float* inv_deg = (float*)ws; ws += (size_t)N_NODES * 4;
    int*   bsum    = (int*)ws;  ws += 256 * 4;
    int*   boff    = (int*)ws;

    const int NB = (N_NODES + 255) / 256;  // 157

    hipMemsetAsync(deg, 0, (size_t)(N_NODES + (N_NODES + 4) + N_NODES) * 4, stream);

    hist_kernel<<<(N_EDGES + 255) / 256, 256, 0, stream>>>(dst, deg);
    scan1_kernel<<<NB, 256, 0, stream>>>(deg, offsets, inv_deg, bsum);
    scan2_kernel<<<1, 256, 0, stream>>>(bsum, boff);
    scan3_kernel<<<NB, 256, 0, stream>>>(offsets, deg, boff);
    scatter_kernel<<<(N_EDGES + 255) / 256, 256, 0, stream>>>(src, dst, offsets, cursor, csr_src);

    const int PREP_ITEMS = N_NODES * DIM / 8 + N_LAYERS * 2 * DIM * DIM;
    prep_kernel<<<(PREP_ITEMS + 255) / 256, 256, 0, stream>>>(x, h, w_self, w_neigh, wt);

    const int GEMM_BLOCKS = (N_NODES + 127) / 128;  // 313
    for (int l = 0; l < N_LAYERS; ++l) {
        agg_kernel<<<(N_NODES * 64 + 255) / 256, 256, 0, stream>>>(
            h, offsets, csr_src, inv_deg, agg);
        int last = (l == N_LAYERS - 1);
        gemm_kernel<<<GEMM_BLOCKS, 256, 0, stream>>>(
            h, agg, wt + (size_t)l * 2 * DIM * DIM,
            b + (size_t)l * DIM,
            out, h,
            last ? 1 : 0, last ? 0 : 1);
    }
}